// Round 5
// baseline (1698.192 us; speedup 1.0000x reference)
//
#include <hip/hip_runtime.h>
#include <math.h>

#define P_TOTAL 147456
#define HW 9216
#define CHW (512*9216)
#define RBLK 16

__device__ __forceinline__ unsigned f2key(float f) {
    unsigned u = __float_as_uint(f);
    return (u & 0x80000000u) ? ~u : (u | 0x80000000u);
}

__device__ __forceinline__ unsigned long long pack2f(float a, float b) {
    return ((unsigned long long)__float_as_uint(a) << 32) | (unsigned long long)__float_as_uint(b);
}

// ---------- K0: protoT [c][128] (j = side*64+k) and pworkT [side][c][64k] ----------
__global__ void k_init(const float* __restrict__ fg, const float* __restrict__ bg,
                       float* __restrict__ protoT, float* __restrict__ pworkT) {
    int i = blockIdx.x * 256 + threadIdx.x;   // 0..65535
    int side = i >> 15;
    int r = i & 32767;
    int k = r >> 9;
    int c = r & 511;
    float v = (side ? bg : fg)[k * 512 + c];
    protoT[c * 128 + side * 64 + k] = v;
    pworkT[side * 32768 + c * 64 + k] = v;
}

// ---------- K1: scoring GEMM + combine + hist1, fused (unchanged from r4) ----------
__global__ __launch_bounds__(512, 2) void k_score(const float* __restrict__ F,
                                                  const float* __restrict__ protoT,
                                                  const float* __restrict__ M,
                                                  float* __restrict__ sfg,
                                                  float* __restrict__ sbg,
                                                  float* __restrict__ invout,
                                                  unsigned* __restrict__ hist) {
    __shared__ float lds[8192];               // 32 KB proto chunk [c][128 j]
    const int t = threadIdx.x;
    const int lane = t & 63;
    const int w = t >> 6;                     // 0..7 ; j range [16w, 16w+16)
    const int p0 = blockIdx.x * 576 + lane;   // 9216 % 576 == 0 -> one image per block
    const int n = p0 / HW;
    const int hw0 = p0 - n * HW;
    const float* Fb = F + (size_t)n * CHW;

    float acc[16][9];
#pragma unroll
    for (int jj = 0; jj < 16; ++jj)
#pragma unroll
        for (int i = 0; i < 9; ++i) acc[jj][i] = 0.f;
    float nn[9];
#pragma unroll
    for (int i = 0; i < 9; ++i) nn[i] = 0.f;

    auto ldch = [&](float (&dst)[9], int ch) {
        int chc = ch > 511 ? 511 : ch;
        const float* q = Fb + hw0 + (size_t)chc * HW;
#pragma unroll
        for (int i = 0; i < 9; ++i) dst[i] = q[i * 64];
    };
    auto kstep = [&](const float (&f)[9], int cc) {
        const float4* pv4 = (const float4*)(lds + cc * 128 + w * 16);
#pragma unroll
        for (int j4 = 0; j4 < 4; ++j4) {
            float4 bq = pv4[j4];
#pragma unroll
            for (int i = 0; i < 9; ++i) {
                acc[j4 * 4 + 0][i] = fmaf(f[i], bq.x, acc[j4 * 4 + 0][i]);
                acc[j4 * 4 + 1][i] = fmaf(f[i], bq.y, acc[j4 * 4 + 1][i]);
                acc[j4 * 4 + 2][i] = fmaf(f[i], bq.z, acc[j4 * 4 + 2][i]);
                acc[j4 * 4 + 3][i] = fmaf(f[i], bq.w, acc[j4 * 4 + 3][i]);
            }
        }
    };

    float fa[9], fb[9];
    ldch(fa, 0); ldch(fb, 1);
    int ch = 2;

    for (int chunk = 0; chunk < 8; ++chunk) {
        __syncthreads();
        {
            const float4* src = (const float4*)(protoT + chunk * 8192);
            float4* dst = (float4*)lds;
#pragma unroll
            for (int i2 = 0; i2 < 4; ++i2) dst[t + 512 * i2] = src[t + 512 * i2];
        }
        __syncthreads();
        for (int c2 = 0; c2 < 32; ++c2) {
            if (w == 0) {
#pragma unroll
                for (int i = 0; i < 9; ++i) nn[i] = fmaf(fa[i], fa[i], nn[i]);
            }
            kstep(fa, c2 * 2);
            ldch(fa, ch++);
            if (w == 0) {
#pragma unroll
                for (int i = 0; i < 9; ++i) nn[i] = fmaf(fb[i], fb[i], nn[i]);
            }
            kstep(fb, c2 * 2 + 1);
            ldch(fb, ch++);
        }
    }

    float m16[9];
#pragma unroll
    for (int i = 0; i < 9; ++i) {
        float mm = acc[0][i];
#pragma unroll
        for (int jj = 1; jj < 16; ++jj) mm = fmaxf(mm, acc[jj][i]);
        m16[i] = mm;
    }
    __syncthreads();
#pragma unroll
    for (int i = 0; i < 9; ++i) lds[w * 576 + i * 64 + lane] = m16[i];
    if (w == 0) {
#pragma unroll
        for (int i = 0; i < 9; ++i) lds[4608 + i * 64 + lane] = nn[i];
    }
    __syncthreads();
    for (int pi = t; pi < 576; pi += 512) {
        int p = blockIdx.x * 576 + pi;
        float fgm = fmaxf(fmaxf(lds[pi], lds[576 + pi]), fmaxf(lds[1152 + pi], lds[1728 + pi]));
        float bgm = fmaxf(fmaxf(lds[2304 + pi], lds[2880 + pi]), fmaxf(lds[3456 + pi], lds[4032 + pi]));
        float inv = 1.f / fmaxf(sqrtf(lds[4608 + pi]), 1e-8f);
        float mm = fminf(fmaxf(M[p], 0.f), 1.f);
        float sf = (1.f - fgm * inv) * mm;
        float sb = (1.f - bgm * inv) * (1.f - mm);
        sfg[p] = sf; sbg[p] = sb; invout[p] = inv;
        atomicAdd(&hist[f2key(sf) >> 16], 1u);
        atomicAdd(&hist[65536 + (f2key(sb) >> 16)], 1u);
    }
}

// ---------- scan / hist2 / collect / finalize (unchanged) ----------
__global__ __launch_bounds__(1024) void k_scan(const unsigned* __restrict__ hist,
                                               int* __restrict__ ctrl, int pass) {
    __shared__ unsigned sd[1024];
    int side = blockIdx.x;
    const unsigned* h = hist + side * 65536;
    int t = threadIdx.x;
    unsigned partial = 0;
    for (int j = 0; j < 64; ++j) partial += h[65535 - (t * 64 + j)];
    sd[t] = partial;
    __syncthreads();
    for (int off = 1; off < 1024; off <<= 1) {
        unsigned v = (t >= off) ? sd[t - off] : 0u;
        __syncthreads();
        sd[t] += v;
        __syncthreads();
    }
    unsigned incl = sd[t];
    unsigned excl = incl - partial;
    unsigned target = (pass == 0) ? 256u : (unsigned)ctrl[side * 8 + 1];
    if (excl < target && target <= incl) {
        unsigned cum = excl;
        for (int j = 0; j < 64; ++j) {
            int b = 65535 - (t * 64 + j);
            unsigned c = h[b];
            if (cum + c >= target) {
                if (pass == 0) {
                    ctrl[side * 8 + 0] = b;
                    ctrl[side * 8 + 1] = (int)(target - cum);
                } else {
                    unsigned vkey = ((unsigned)ctrl[side * 8 + 0] << 16) | (unsigned)b;
                    ctrl[side * 8 + 2] = (int)vkey;
                    int n_gt = (int)(256u - (unsigned)ctrl[side * 8 + 1] + cum);
                    ctrl[side * 8 + 3] = n_gt;
                    ctrl[side * 8 + 4] = 256 - n_gt;
                }
                break;
            }
            cum += c;
        }
    }
}

__global__ void k_hist2(const float* __restrict__ sfg, const float* __restrict__ sbg,
                        const int* __restrict__ ctrl, unsigned* __restrict__ hist2) {
    int side = blockIdx.y;
    int p = blockIdx.x * 256 + threadIdx.x;
    float s = side ? sbg[p] : sfg[p];
    unsigned key = f2key(s);
    if ((int)(key >> 16) == ctrl[side * 8 + 0])
        atomicAdd(&hist2[side * 65536 + (key & 0xffffu)], 1u);
}

__global__ void k_collect(const float* __restrict__ sfg, const float* __restrict__ sbg,
                          int* __restrict__ ctrl, int* __restrict__ idx, int* __restrict__ ties) {
    int side = blockIdx.y;
    int p = blockIdx.x * 256 + threadIdx.x;
    float s = side ? sbg[p] : sfg[p];
    unsigned key = f2key(s);
    unsigned vkey = (unsigned)ctrl[side * 8 + 2];
    if (key > vkey) {
        int pos = atomicAdd(&ctrl[side * 8 + 5], 1);
        idx[side * 256 + pos] = p;
    } else if (key == vkey) {
        int pos = atomicAdd(&ctrl[side * 8 + 6], 1);
        if (pos < 512) ties[side * 512 + pos] = p;
    }
}

__global__ void k_finalize(int* __restrict__ ctrl, int* __restrict__ idx, int* __restrict__ ties) {
    int side = threadIdx.x;
    if (side >= 2) return;
    int n_gt = ctrl[side * 8 + 3];
    int need = ctrl[side * 8 + 4];
    int cnt = ctrl[side * 8 + 6];
    if (cnt > 512) cnt = 512;
    int* tb = ties + side * 512;
    for (int q = 0; q < need; ++q) {
        int mi = q;
        for (int j = q + 1; j < cnt; ++j) if (tb[j] < tb[mi]) mi = j;
        int tmp = tb[q]; tb[q] = tb[mi]; tb[mi] = tmp;
        idx[side * 256 + n_gt + q] = tb[q];
    }
}

// ---------- gather normalized selected features (+ transposed copy) ----------
__global__ void k_gather(const float* __restrict__ F, const float* __restrict__ inv,
                         const int* __restrict__ idx, float* __restrict__ feats,
                         float* __restrict__ featsT) {
    int b = blockIdx.x;              // 0..511
    int side = b >> 8, j = b & 255;
    int p = idx[side * 256 + j];
    float iv = inv[p];
    int n = p / HW, hw = p - n * HW;
    const float* Fp = F + (size_t)n * CHW + hw;
    int gr = side * 256 + j;
    float* o = feats + (size_t)gr * 512;
    for (int c = threadIdx.x; c < 512; c += 256) {
        float v = Fp[(size_t)c * HW] * iv;
        o[c] = v;
        featsT[(size_t)c * 512 + gr] = v;
    }
}

// ---------- fused refine (10 iters) + losspart + final + refined ----------
// 16 blocks = 2 sides x 8 cluster-octets; 256 thr (lane=row). Each block owns
// its 8 clusters PRIVATELY in pwbuf[blk][iter][c][8] (fresh address per iter ->
// no cache staleness; wave-uniform reads -> scalar path). Cross-block traffic:
// only 256 packed (maxval,idx) u64 per block per iter + tail partials, via
// agent-scope atomics. One grid barrier per iteration (11 total).
__global__ __launch_bounds__(256, 1) void k_refine(const float* __restrict__ feats,
                                                   const float* __restrict__ featsT,
                                                   const float* __restrict__ pworkT,
                                                   const float* __restrict__ fg,
                                                   const float* __restrict__ bg,
                                                   float* __restrict__ pwbuf,
                                                   unsigned long long* __restrict__ part,
                                                   unsigned long long* __restrict__ d1p,
                                                   unsigned long long* __restrict__ d2p,
                                                   float* __restrict__ out,
                                                   int* __restrict__ bar) {
    __shared__ int asg[256];
    __shared__ float red[12];
    const int t = threadIdx.x;
    const int lane = t & 63;
    const int w = t >> 6;
    const int blk = blockIdx.x;
    const int side = blk >> 3;
    const int oct = blk & 7;
    float* mypw = pwbuf + (size_t)blk * 11 * 4096;   // [iter][c*8 + klocal]

    // prologue: private proto copy, layout [c][8]
    for (int e = t; e < 4096; e += 256) {
        int c = e >> 3, kl = e & 7;
        mypw[e] = pworkT[side * 32768 + c * 64 + oct * 8 + kl];
    }
    __syncthreads();

    auto gbar = [&](int e) {
        __syncthreads();
        __threadfence();
        if (t == 0) atomicAdd(bar, 1);
        if (w == 0) {
            while (__hip_atomic_load(bar, __ATOMIC_RELAXED, __HIP_MEMORY_SCOPE_AGENT) < e * RBLK)
                __builtin_amdgcn_s_sleep(2);
        }
        __syncthreads();
        __threadfence();
    };

    // acc[k] = sum_c featsT[c][grow] * pw[c*8+k], c ascending (bit-exact dot order)
    auto dot8 = [&](const float* pw, int grow, float (&acc)[8]) {
#pragma unroll
        for (int k = 0; k < 8; ++k) acc[k] = 0.f;
#pragma unroll 4
        for (int c = 0; c < 512; ++c) {
            float f = featsT[(size_t)c * 512 + grow];
            const float* pc = pw + c * 8;
#pragma unroll
            for (int k = 0; k < 8; ++k) acc[k] = fmaf(f, pc[k], acc[k]);
        }
    };

    int ep = 0;
    for (int it = 0; it < 10; ++it) {
        const float* pwo = mypw + it * 4096;
        // ---- assign dots: this thread = row t of this side ----
        float acc[8];
        dot8(pwo, side * 256 + t, acc);
        float pm = acc[0]; int pi = 0;
#pragma unroll
        for (int k = 1; k < 8; ++k) if (acc[k] > pm) { pm = acc[k]; pi = k; }
        int pbuf = it & 1;
        __hip_atomic_store(&part[((size_t)(pbuf * 2 + side) * 8 + oct) * 256 + t],
                           pack2f(pm, __uint_as_float((unsigned)(oct * 8 + pi))),
                           __ATOMIC_RELAXED, __HIP_MEMORY_SCOPE_AGENT);
        gbar(++ep);
        // ---- combine argmax (first-max over octs ascending = jnp.argmax) ----
        {
            float bv; int bi;
            unsigned long long q0 = __hip_atomic_load(
                &part[((size_t)(pbuf * 2 + side) * 8 + 0) * 256 + t],
                __ATOMIC_RELAXED, __HIP_MEMORY_SCOPE_AGENT);
            bv = __uint_as_float((unsigned)(q0 >> 32));
            bi = (int)(unsigned)(q0 & 0xffffffffu) >= 0 ? (int)__float_as_uint(__uint_as_float((unsigned)(q0 & 0xffffffffu))) : 0;
            bi = (int)__float_as_uint(__uint_as_float((unsigned)(q0 & 0xffffffffu)));
            for (int o = 1; o < 8; ++o) {
                unsigned long long q = __hip_atomic_load(
                    &part[((size_t)(pbuf * 2 + side) * 8 + o) * 256 + t],
                    __ATOMIC_RELAXED, __HIP_MEMORY_SCOPE_AGENT);
                float qv = __uint_as_float((unsigned)(q >> 32));
                if (qv > bv) { bv = qv; bi = (int)__float_as_uint(__uint_as_float((unsigned)(q & 0xffffffffu))); }
            }
            asg[t] = bi;
        }
        __syncthreads();
        // ---- sums + update for this block's 8 clusters (2 per wave) ----
        float step = (float)(0.1 / (1.0 + 0.5 * (double)it));
        float* pwn = mypw + (it + 1) * 4096;
        for (int q = 0; q < 2; ++q) {
            int kl = w * 2 + q;
            int kg = oct * 8 + kl;
            float s8[8]; int cnt = 0;
#pragma unroll
            for (int i = 0; i < 8; ++i) s8[i] = 0.f;
            for (int r = 0; r < 256; ++r) {
                if (asg[r] == kg) {
                    ++cnt;
                    const float* fr = feats + (size_t)(side * 256 + r) * 512;
#pragma unroll
                    for (int i = 0; i < 8; ++i) s8[i] += fr[lane + i * 64];
                }
            }
            float nf = fmaxf((float)cnt, 1.f);
            float bl[8]; float n2 = 0.f;
#pragma unroll
            for (int i = 0; i < 8; ++i) {
                int c = lane + i * 64;
                float mean = s8[i] / nf;
                float pv = pwo[c * 8 + kl];
                float v = (1.f - step) * pv + step * mean;
                bl[i] = v; n2 = fmaf(v, v, n2);
            }
#pragma unroll
            for (int m = 32; m >= 1; m >>= 1) n2 += __shfl_xor(n2, m);
            float inv = 1.f / fmaxf(sqrtf(n2), 1e-8f);
#pragma unroll
            for (int i = 0; i < 8; ++i) {
                int c = lane + i * 64;
                pwn[c * 8 + kl] = (cnt > 0) ? bl[i] * inv : pwo[c * 8 + kl];
            }
        }
        __syncthreads();
    }

    const float* pwf = mypw + 10 * 4096;

    // ---- refined protos for this block's 8 clusters (exact k_refined math) ----
    for (int q = 0; q < 2; ++q) {
        int kl = w * 2 + q;
        int kg = oct * 8 + kl;
        const float* proto = (side ? bg : fg) + (size_t)kg * 512;
        float bl[8]; float n2 = 0.f;
#pragma unroll
        for (int i = 0; i < 8; ++i) {
            int c = lane + i * 64;
            float v = 0.7f * proto[c] + 0.3f * pwf[c * 8 + kl];
            bl[i] = v; n2 = fmaf(v, v, n2);
        }
#pragma unroll
        for (int m = 32; m >= 1; m >>= 1) n2 += __shfl_xor(n2, m);
        float inv = 1.f / fmaxf(sqrtf(n2), 1e-8f);
#pragma unroll
        for (int i = 0; i < 8; ++i)
            out[1 + side * 32768 + kg * 512 + lane + i * 64] = bl[i] * inv;
    }

    // ---- losspart partials: per-oct (max, sum-exp) ----
    const float inv_tau = 1.f / 0.07f;
    if (side == 0) {
        for (int h = 0; h < 2; ++h) {
            int r = h * 256 + t;          // global row 0..511 vs p_fg octet
            float a8[8];
            dot8(pwf, r, a8);
            float pm = a8[0];
#pragma unroll
            for (int k = 1; k < 8; ++k) pm = fmaxf(pm, a8[k]);
            float se = 0.f;
#pragma unroll
            for (int k = 0; k < 8; ++k) se += expf((a8[k] - pm) * inv_tau);
            __hip_atomic_store(&d1p[(size_t)oct * 512 + r], pack2f(pm, se),
                               __ATOMIC_RELAXED, __HIP_MEMORY_SCOPE_AGENT);
        }
    } else {
        float a8[8];
        dot8(pwf, t, a8);                 // pos row t vs p_bg octet
        float pm = a8[0];
#pragma unroll
        for (int k = 1; k < 8; ++k) pm = fmaxf(pm, a8[k]);
        float se = 0.f;
#pragma unroll
        for (int k = 0; k < 8; ++k) se += expf((a8[k] - pm) * inv_tau);
        __hip_atomic_store(&d2p[(size_t)oct * 256 + t], pack2f(pm, se),
                           __ATOMIC_RELAXED, __HIP_MEMORY_SCOPE_AGENT);
    }
    gbar(++ep);

    // ---- final scalar loss (block 0) ----
    if (blk == 0) {
        // pos row t
        float m1 = -3.4e38f, sn = 0.f;
        float pmo[8], seo[8];
        for (int o = 0; o < 8; ++o) {
            unsigned long long q = __hip_atomic_load(&d1p[(size_t)o * 512 + t],
                                                     __ATOMIC_RELAXED, __HIP_MEMORY_SCOPE_AGENT);
            pmo[o] = __uint_as_float((unsigned)(q >> 32));
            seo[o] = __uint_as_float((unsigned)(q & 0xffffffffu));
            m1 = fmaxf(m1, pmo[o]);
        }
        for (int o = 0; o < 8; ++o) sn += seo[o] * expf((pmo[o] - m1) * inv_tau);
        float smax = m1;                  // exact raw max for triplet
        float mb = -3.4e38f, sb = 0.f;
        float pmb[8], seb[8];
        for (int o = 0; o < 8; ++o) {
            unsigned long long q = __hip_atomic_load(&d2p[(size_t)o * 256 + t],
                                                     __ATOMIC_RELAXED, __HIP_MEMORY_SCOPE_AGENT);
            pmb[o] = __uint_as_float((unsigned)(q >> 32));
            seb[o] = __uint_as_float((unsigned)(q & 0xffffffffu));
            mb = fmaxf(mb, pmb[o]);
        }
        for (int o = 0; o < 8; ++o) sb += seb[o] * expf((pmb[o] - mb) * inv_tau);
        float a1 = m1 * inv_tau, ab = mb * inv_tau;
        float md = fmaxf(a1, ab);
        float sdn = sn * expf(a1 - md) + sb * expf(ab - md);
        float nmr = (a1 + logf(sn)) - (md + logf(sdn));
        // neg row 256+t: max sim vs p_fg
        float snr = -3.4e38f;
        for (int o = 0; o < 8; ++o) {
            unsigned long long q = __hip_atomic_load(&d1p[(size_t)o * 512 + 256 + t],
                                                     __ATOMIC_RELAXED, __HIP_MEMORY_SCOPE_AGENT);
            snr = fmaxf(snr, __uint_as_float((unsigned)(q >> 32)));
        }
        float sp = smax, sv = snr, nm = nmr;
#pragma unroll
        for (int m = 32; m >= 1; m >>= 1) {
            sp += __shfl_xor(sp, m); sv += __shfl_xor(sv, m); nm += __shfl_xor(nm, m);
        }
        if (lane == 0) { red[w] = sp; red[4 + w] = sv; red[8 + w] = nm; }
        __syncthreads();
        if (t == 0) {
            float SP = 0, SN = 0, NM = 0;
            for (int i = 0; i < 4; ++i) { SP += red[i]; SN += red[4 + i]; NM += red[8 + i]; }
            SP /= 256.f; SN /= 256.f; NM /= 256.f;
            out[0] = fmaxf(0.f, 0.2f + SN - SP) + 0.25f * (-NM);
        }
    }
}

extern "C" void kernel_launch(void* const* d_in, const int* in_sizes, int n_in,
                              void* d_out, int out_size, void* d_ws, size_t ws_size,
                              hipStream_t stream) {
    const float* fg = (const float*)d_in[0];
    const float* bg = (const float*)d_in[1];
    const float* F  = (const float*)d_in[2];
    const float* M  = (const float*)d_in[3];
    float* out = (float*)d_out;
    char* ws = (char*)d_ws;

    size_t o = 0;
    auto alloc = [&](size_t bytes) { size_t r = o; o += (bytes + 1023) & ~(size_t)1023; return r; };
    // zero region
    size_t off_hist1 = alloc(2 * 65536 * 4);
    size_t off_hist2 = alloc(2 * 65536 * 4);
    size_t off_ctrl  = alloc(64);
    size_t off_bar   = alloc(64);
    size_t zbytes = o;
    size_t off_sfg   = alloc(P_TOTAL * 4);
    size_t off_sbg   = alloc(P_TOTAL * 4);
    size_t off_inv   = alloc(P_TOTAL * 4);
    size_t off_pT    = alloc(512 * 128 * 4);
    size_t off_pwT   = alloc(2 * 64 * 512 * 4);
    size_t off_idx   = alloc(2 * 256 * 4);
    size_t off_ties  = alloc(2 * 512 * 4);
    size_t off_feats = alloc(512 * 512 * 4);
    size_t off_featsT= alloc(512 * 512 * 4);
    size_t off_pwbuf = alloc((size_t)RBLK * 11 * 4096 * 4);
    size_t off_part  = alloc(2 * 2 * 8 * 256 * 8);
    size_t off_d1p   = alloc(8 * 512 * 8);
    size_t off_d2p   = alloc(8 * 256 * 8);

    unsigned* hist1 = (unsigned*)(ws + off_hist1);
    unsigned* hist2 = (unsigned*)(ws + off_hist2);
    int* ctrl   = (int*)(ws + off_ctrl);
    int* bar    = (int*)(ws + off_bar);
    float* sfg  = (float*)(ws + off_sfg);
    float* sbg  = (float*)(ws + off_sbg);
    float* inv  = (float*)(ws + off_inv);
    float* pT   = (float*)(ws + off_pT);
    float* pwT  = (float*)(ws + off_pwT);
    int* idx    = (int*)(ws + off_idx);
    int* ties   = (int*)(ws + off_ties);
    float* feats  = (float*)(ws + off_feats);
    float* featsT = (float*)(ws + off_featsT);
    float* pwbuf  = (float*)(ws + off_pwbuf);
    unsigned long long* part = (unsigned long long*)(ws + off_part);
    unsigned long long* d1p  = (unsigned long long*)(ws + off_d1p);
    unsigned long long* d2p  = (unsigned long long*)(ws + off_d2p);

    hipMemsetAsync(ws, 0, zbytes, stream);
    k_init<<<256, 256, 0, stream>>>(fg, bg, pT, pwT);
    k_score<<<256, 512, 0, stream>>>(F, pT, M, sfg, sbg, inv, hist1);
    k_scan<<<2, 1024, 0, stream>>>(hist1, ctrl, 0);
    k_hist2<<<dim3(576, 2), 256, 0, stream>>>(sfg, sbg, ctrl, hist2);
    k_scan<<<2, 1024, 0, stream>>>(hist2, ctrl, 1);
    k_collect<<<dim3(576, 2), 256, 0, stream>>>(sfg, sbg, ctrl, idx, ties);
    k_finalize<<<1, 64, 0, stream>>>(ctrl, idx, ties);
    k_gather<<<512, 256, 0, stream>>>(F, inv, idx, feats, featsT);
    k_refine<<<RBLK, 256, 0, stream>>>(feats, featsT, pwT, fg, bg,
                                       pwbuf, part, d1p, d2p, out, bar);
}

// Round 6
// 1435.429 us; speedup vs baseline: 1.1831x; 1.1831x over previous
//
#include <hip/hip_runtime.h>
#include <math.h>

#define P_TOTAL 147456
#define HW 9216
#define CHW (512*9216)
#define SW(c,k) ((c)*64 + (((k)+(c)) & 63))

__device__ __forceinline__ unsigned f2key(float f) {
    unsigned u = __float_as_uint(f);
    return (u & 0x80000000u) ? ~u : (u | 0x80000000u);
}
__device__ __forceinline__ float agload(const float* p) {
    return __hip_atomic_load(p, __ATOMIC_RELAXED, __HIP_MEMORY_SCOPE_AGENT);
}
__device__ __forceinline__ void agstoref(float* p, float v) {
    __hip_atomic_store(p, v, __ATOMIC_RELAXED, __HIP_MEMORY_SCOPE_AGENT);
}
__device__ __forceinline__ unsigned long long agload64(const unsigned long long* p) {
    return __hip_atomic_load(p, __ATOMIC_RELAXED, __HIP_MEMORY_SCOPE_AGENT);
}
__device__ __forceinline__ void agstore64(unsigned long long* p, unsigned long long v) {
    __hip_atomic_store(p, v, __ATOMIC_RELAXED, __HIP_MEMORY_SCOPE_AGENT);
}
__device__ __forceinline__ unsigned long long pack2f(float a, float b) {
    return ((unsigned long long)__float_as_uint(a) << 32) | (unsigned long long)__float_as_uint(b);
}

// ---------- K0: protoT [c][128] (j = side*64+k) and pworkT [side][c][64k] ----------
__global__ void k_init(const float* __restrict__ fg, const float* __restrict__ bg,
                       float* __restrict__ protoT, float* __restrict__ pworkT) {
    int i = blockIdx.x * 256 + threadIdx.x;   // 0..65535
    int side = i >> 15;
    int r = i & 32767;
    int k = r >> 9;
    int c = r & 511;
    float v = (side ? bg : fg)[k * 512 + c];
    protoT[c * 128 + side * 64 + k] = v;
    pworkT[side * 32768 + c * 64 + k] = v;
}

// ---------- K1: scoring GEMM + combine + hist1, fused (unchanged, passed r4/r5) ----------
__global__ __launch_bounds__(512, 2) void k_score(const float* __restrict__ F,
                                                  const float* __restrict__ protoT,
                                                  const float* __restrict__ M,
                                                  float* __restrict__ sfg,
                                                  float* __restrict__ sbg,
                                                  float* __restrict__ invout,
                                                  unsigned* __restrict__ hist) {
    __shared__ float lds[8192];               // 32 KB proto chunk [c][128 j]
    const int t = threadIdx.x;
    const int lane = t & 63;
    const int w = t >> 6;                     // 0..7 ; j range [16w, 16w+16)
    const int p0 = blockIdx.x * 576 + lane;   // 9216 % 576 == 0 -> one image per block
    const int n = p0 / HW;
    const int hw0 = p0 - n * HW;
    const float* Fb = F + (size_t)n * CHW;

    float acc[16][9];
#pragma unroll
    for (int jj = 0; jj < 16; ++jj)
#pragma unroll
        for (int i = 0; i < 9; ++i) acc[jj][i] = 0.f;
    float nn[9];
#pragma unroll
    for (int i = 0; i < 9; ++i) nn[i] = 0.f;

    auto ldch = [&](float (&dst)[9], int ch) {
        int chc = ch > 511 ? 511 : ch;
        const float* q = Fb + hw0 + (size_t)chc * HW;
#pragma unroll
        for (int i = 0; i < 9; ++i) dst[i] = q[i * 64];
    };
    auto kstep = [&](const float (&f)[9], int cc) {
        const float4* pv4 = (const float4*)(lds + cc * 128 + w * 16);
#pragma unroll
        for (int j4 = 0; j4 < 4; ++j4) {
            float4 bq = pv4[j4];
#pragma unroll
            for (int i = 0; i < 9; ++i) {
                acc[j4 * 4 + 0][i] = fmaf(f[i], bq.x, acc[j4 * 4 + 0][i]);
                acc[j4 * 4 + 1][i] = fmaf(f[i], bq.y, acc[j4 * 4 + 1][i]);
                acc[j4 * 4 + 2][i] = fmaf(f[i], bq.z, acc[j4 * 4 + 2][i]);
                acc[j4 * 4 + 3][i] = fmaf(f[i], bq.w, acc[j4 * 4 + 3][i]);
            }
        }
    };

    float fa[9], fb[9];
    ldch(fa, 0); ldch(fb, 1);
    int ch = 2;

    for (int chunk = 0; chunk < 8; ++chunk) {
        __syncthreads();
        {
            const float4* src = (const float4*)(protoT + chunk * 8192);
            float4* dst = (float4*)lds;
#pragma unroll
            for (int i2 = 0; i2 < 4; ++i2) dst[t + 512 * i2] = src[t + 512 * i2];
        }
        __syncthreads();
        for (int c2 = 0; c2 < 32; ++c2) {
            if (w == 0) {
#pragma unroll
                for (int i = 0; i < 9; ++i) nn[i] = fmaf(fa[i], fa[i], nn[i]);
            }
            kstep(fa, c2 * 2);
            ldch(fa, ch++);
            if (w == 0) {
#pragma unroll
                for (int i = 0; i < 9; ++i) nn[i] = fmaf(fb[i], fb[i], nn[i]);
            }
            kstep(fb, c2 * 2 + 1);
            ldch(fb, ch++);
        }
    }

    float m16[9];
#pragma unroll
    for (int i = 0; i < 9; ++i) {
        float mm = acc[0][i];
#pragma unroll
        for (int jj = 1; jj < 16; ++jj) mm = fmaxf(mm, acc[jj][i]);
        m16[i] = mm;
    }
    __syncthreads();
#pragma unroll
    for (int i = 0; i < 9; ++i) lds[w * 576 + i * 64 + lane] = m16[i];
    if (w == 0) {
#pragma unroll
        for (int i = 0; i < 9; ++i) lds[4608 + i * 64 + lane] = nn[i];
    }
    __syncthreads();
    for (int pi = t; pi < 576; pi += 512) {
        int p = blockIdx.x * 576 + pi;
        float fgm = fmaxf(fmaxf(lds[pi], lds[576 + pi]), fmaxf(lds[1152 + pi], lds[1728 + pi]));
        float bgm = fmaxf(fmaxf(lds[2304 + pi], lds[2880 + pi]), fmaxf(lds[3456 + pi], lds[4032 + pi]));
        float inv = 1.f / fmaxf(sqrtf(lds[4608 + pi]), 1e-8f);
        float mm = fminf(fmaxf(M[p], 0.f), 1.f);
        float sf = (1.f - fgm * inv) * mm;
        float sb = (1.f - bgm * inv) * (1.f - mm);
        sfg[p] = sf; sbg[p] = sb; invout[p] = inv;
        atomicAdd(&hist[f2key(sf) >> 16], 1u);
        atomicAdd(&hist[65536 + (f2key(sb) >> 16)], 1u);
    }
}

// ---------- scan / hist2 / collect / finalize (unchanged) ----------
__global__ __launch_bounds__(1024) void k_scan(const unsigned* __restrict__ hist,
                                               int* __restrict__ ctrl, int pass) {
    __shared__ unsigned sd[1024];
    int side = blockIdx.x;
    const unsigned* h = hist + side * 65536;
    int t = threadIdx.x;
    unsigned partial = 0;
    for (int j = 0; j < 64; ++j) partial += h[65535 - (t * 64 + j)];
    sd[t] = partial;
    __syncthreads();
    for (int off = 1; off < 1024; off <<= 1) {
        unsigned v = (t >= off) ? sd[t - off] : 0u;
        __syncthreads();
        sd[t] += v;
        __syncthreads();
    }
    unsigned incl = sd[t];
    unsigned excl = incl - partial;
    unsigned target = (pass == 0) ? 256u : (unsigned)ctrl[side * 8 + 1];
    if (excl < target && target <= incl) {
        unsigned cum = excl;
        for (int j = 0; j < 64; ++j) {
            int b = 65535 - (t * 64 + j);
            unsigned c = h[b];
            if (cum + c >= target) {
                if (pass == 0) {
                    ctrl[side * 8 + 0] = b;
                    ctrl[side * 8 + 1] = (int)(target - cum);
                } else {
                    unsigned vkey = ((unsigned)ctrl[side * 8 + 0] << 16) | (unsigned)b;
                    ctrl[side * 8 + 2] = (int)vkey;
                    int n_gt = (int)(256u - (unsigned)ctrl[side * 8 + 1] + cum);
                    ctrl[side * 8 + 3] = n_gt;
                    ctrl[side * 8 + 4] = 256 - n_gt;
                }
                break;
            }
            cum += c;
        }
    }
}

__global__ void k_hist2(const float* __restrict__ sfg, const float* __restrict__ sbg,
                        const int* __restrict__ ctrl, unsigned* __restrict__ hist2) {
    int side = blockIdx.y;
    int p = blockIdx.x * 256 + threadIdx.x;
    float s = side ? sbg[p] : sfg[p];
    unsigned key = f2key(s);
    if ((int)(key >> 16) == ctrl[side * 8 + 0])
        atomicAdd(&hist2[side * 65536 + (key & 0xffffu)], 1u);
}

__global__ void k_collect(const float* __restrict__ sfg, const float* __restrict__ sbg,
                          int* __restrict__ ctrl, int* __restrict__ idx, int* __restrict__ ties) {
    int side = blockIdx.y;
    int p = blockIdx.x * 256 + threadIdx.x;
    float s = side ? sbg[p] : sfg[p];
    unsigned key = f2key(s);
    unsigned vkey = (unsigned)ctrl[side * 8 + 2];
    if (key > vkey) {
        int pos = atomicAdd(&ctrl[side * 8 + 5], 1);
        idx[side * 256 + pos] = p;
    } else if (key == vkey) {
        int pos = atomicAdd(&ctrl[side * 8 + 6], 1);
        if (pos < 512) ties[side * 512 + pos] = p;
    }
}

__global__ void k_finalize(int* __restrict__ ctrl, int* __restrict__ idx, int* __restrict__ ties) {
    int side = threadIdx.x;
    if (side >= 2) return;
    int n_gt = ctrl[side * 8 + 3];
    int need = ctrl[side * 8 + 4];
    int cnt = ctrl[side * 8 + 6];
    if (cnt > 512) cnt = 512;
    int* tb = ties + side * 512;
    for (int q = 0; q < need; ++q) {
        int mi = q;
        for (int j = q + 1; j < cnt; ++j) if (tb[j] < tb[mi]) mi = j;
        int tmp = tb[q]; tb[q] = tb[mi]; tb[mi] = tmp;
        idx[side * 256 + n_gt + q] = tb[q];
    }
}

// ---------- gather normalized selected features ----------
__global__ void k_gather(const float* __restrict__ F, const float* __restrict__ inv,
                         const int* __restrict__ idx, float* __restrict__ feats) {
    int b = blockIdx.x;              // 0..511
    int side = b >> 8, j = b & 255;
    int p = idx[side * 256 + j];
    float iv = inv[p];
    int n = p / HW, hw = p - n * HW;
    const float* Fp = F + (size_t)n * CHW + hw;
    float* o = feats + (size_t)(side * 256 + j) * 512;
    for (int c = threadIdx.x; c < 512; c += 256)
        o[c] = Fp[(size_t)c * HW] * iv;
}

// ---------- persistent refine: 256 blocks (1/CU), side replica in 128KB LDS ----------
// Block blk: side = blk>>7, half = blk&127. LDS holds side's full [512c][64k] pwork
// (swizzled SW(c,k) -> 2-way banks for both access patterns). Assign: waves 0,1 do
// rows side*256+2*half+{0,1} (full ascending fmaf chain, r3-identical). Sums/counts:
// canonical device atomics into per-iteration pre-zeroed slices (no zero phase ->
// ONE grid barrier per iteration). Update: all 4 waves redo all 64 clusters
// redundantly from canonical sums -> identical replicas, no proto write-back.
__global__ __launch_bounds__(256, 1) void k_refine(const float* __restrict__ feats,
                                                   const float* __restrict__ pworkT,
                                                   const float* __restrict__ fg,
                                                   const float* __restrict__ bg,
                                                   float* __restrict__ sums10,
                                                   float* __restrict__ cnts10,
                                                   unsigned long long* __restrict__ lp1,
                                                   unsigned long long* __restrict__ lp2,
                                                   float* __restrict__ lp3,
                                                   float* __restrict__ out,
                                                   int* __restrict__ bar) {
    __shared__ float pw[32768];      // 128 KB
    __shared__ float red[12];
    const int t = threadIdx.x, lane = t & 63, w = t >> 6;
    const int blk = blockIdx.x;
    const int side = blk >> 7;
    const int half = blk & 127;

    for (int e = t; e < 32768; e += 256) {
        int c = e >> 6, k = e & 63;
        pw[SW(c, k)] = pworkT[side * 32768 + e];
    }
    __syncthreads();

    auto gbar = [&](int e) {
        __syncthreads();
        __threadfence();
        if (t == 0) {
            atomicAdd(bar, 1);
            while (__hip_atomic_load(bar, __ATOMIC_RELAXED, __HIP_MEMORY_SCOPE_AGENT) < e * 256)
                __builtin_amdgcn_s_sleep(4);
        }
        __syncthreads();
        __threadfence();
    };

    // full-row dot vs this side's 64 clusters; lane = cluster; ascending c chain
    auto rowdot = [&](int row) -> float {
        const float4* fr4 = (const float4*)(feats + (size_t)row * 512);
        float acc = 0.f;
        for (int c4 = 0; c4 < 128; ++c4) {
            float4 a = fr4[c4];
            int c = c4 * 4;
            acc = fmaf(a.x, pw[SW(c + 0, lane)], acc);
            acc = fmaf(a.y, pw[SW(c + 1, lane)], acc);
            acc = fmaf(a.z, pw[SW(c + 2, lane)], acc);
            acc = fmaf(a.w, pw[SW(c + 3, lane)], acc);
        }
        return acc;
    };

    int ep = 0;
    for (int it = 0; it < 10; ++it) {
        float* sums = sums10 + it * 65536;
        float* cnts = cnts10 + it * 128;
        if (w < 2) {
            int row = side * 256 + half * 2 + w;
            float acc = rowdot(row);
            float bv = acc; int bi = lane;
#pragma unroll
            for (int m = 32; m >= 1; m >>= 1) {
                float ov = __shfl_xor(bv, m);
                int oi = __shfl_xor(bi, m);
                if (ov > bv || (ov == bv && oi < bi)) { bv = ov; bi = oi; }
            }
            if (lane == 0) atomicAdd(&cnts[side * 64 + bi], 1.f);
            const float* frf = feats + (size_t)row * 512;
            float* srow = sums + side * 32768 + bi * 512;
#pragma unroll
            for (int i = 0; i < 8; ++i)
                atomicAdd(&srow[lane + i * 64], frf[lane + i * 64]);
        }
        gbar(++ep);
        float step = (float)(0.1 / (1.0 + 0.5 * (double)it));
        for (int q = 0; q < 16; ++q) {
            int k = w * 16 + q;
            float cnt = agload(&cnts[side * 64 + k]);
            const float* srow = sums + side * 32768 + k * 512;
            float bl[8]; float n2 = 0.f;
#pragma unroll
            for (int i = 0; i < 8; ++i) {
                int c = lane + i * 64;
                float mean = agload(&srow[c]) / fmaxf(cnt, 1.f);
                float v = (1.f - step) * pw[SW(c, k)] + step * mean;
                bl[i] = v; n2 = fmaf(v, v, n2);
            }
#pragma unroll
            for (int m = 32; m >= 1; m >>= 1) n2 += __shfl_xor(n2, m);
            float inv = 1.f / fmaxf(sqrtf(n2), 1e-8f);
            if (cnt > 0.f) {
#pragma unroll
                for (int i = 0; i < 8; ++i) {
                    int c = lane + i * 64;
                    pw[SW(c, k)] = bl[i] * inv;
                }
            }
        }
        __syncthreads();
    }

    // ---- refined protos: blocks 0..63 -> side0 cluster=blk; 128..191 -> side1 ----
    if (half < 64 && w == 0) {
        int k = half;
        const float* proto = (side ? bg : fg) + (size_t)k * 512;
        float bl[8]; float n2 = 0.f;
#pragma unroll
        for (int i = 0; i < 8; ++i) {
            int c = lane + i * 64;
            float v = 0.7f * proto[c] + 0.3f * pw[SW(c, k)];
            bl[i] = v; n2 = fmaf(v, v, n2);
        }
#pragma unroll
        for (int m = 32; m >= 1; m >>= 1) n2 += __shfl_xor(n2, m);
        float inv = 1.f / fmaxf(sqrtf(n2), 1e-8f);
#pragma unroll
        for (int i = 0; i < 8; ++i)
            out[1 + side * 32768 + k * 512 + lane + i * 64] = bl[i] * inv;
    }

    // ---- loss partials ----
    {
        int row = -1;
        if (side == 0) row = (w < 2) ? (half * 2 + w) : (256 + half * 2 + (w - 2));
        else if (w < 2) row = half * 2 + w;
        if (row >= 0) {
            float acc = rowdot(row);      // vs this side's final protos
            if (side == 0) {
                if (row < 256) {          // pos row: smax + fg logsumexp partial
                    float smax = acc;
#pragma unroll
                    for (int m = 32; m >= 1; m >>= 1) smax = fmaxf(smax, __shfl_xor(smax, m));
                    float a = acc / 0.07f;
                    float m1 = a;
#pragma unroll
                    for (int m = 32; m >= 1; m >>= 1) m1 = fmaxf(m1, __shfl_xor(m1, m));
                    float sn = expf(a - m1);
#pragma unroll
                    for (int m = 32; m >= 1; m >>= 1) sn += __shfl_xor(sn, m);
                    if (lane == 0) agstore64(&lp1[row], pack2f(smax, sn));
                } else {                  // neg row: smax vs fg only
                    float smax = acc;
#pragma unroll
                    for (int m = 32; m >= 1; m >>= 1) smax = fmaxf(smax, __shfl_xor(smax, m));
                    if (lane == 0) agstoref(&lp3[row - 256], smax);
                }
            } else {                      // side1: pos row vs bg
                float b = acc / 0.07f;
                float mb = b;
#pragma unroll
                for (int m = 32; m >= 1; m >>= 1) mb = fmaxf(mb, __shfl_xor(mb, m));
                float sb = expf(b - mb);
#pragma unroll
                for (int m = 32; m >= 1; m >>= 1) sb += __shfl_xor(sb, m);
                if (lane == 0) agstore64(&lp2[row], pack2f(mb, sb));
            }
        }
    }
    gbar(++ep);

    // ---- final scalar loss (block 0) ----
    if (blk == 0) {
        unsigned long long q1 = agload64(&lp1[t]);
        unsigned long long q2 = agload64(&lp2[t]);
        float smax = __uint_as_float((unsigned)(q1 >> 32));
        float sn   = __uint_as_float((unsigned)(q1 & 0xffffffffu));
        float mb   = __uint_as_float((unsigned)(q2 >> 32));
        float sb   = __uint_as_float((unsigned)(q2 & 0xffffffffu));
        float snr  = agload(&lp3[t]);
        float m1 = smax / 0.07f;
        float md = fmaxf(m1, mb);
        float sdn = sn * expf(m1 - md) + sb * expf(mb - md);
        float nm = (m1 + logf(sn)) - (md + logf(sdn));
        float sp = smax, sv = snr;
#pragma unroll
        for (int m = 32; m >= 1; m >>= 1) {
            sp += __shfl_xor(sp, m); sv += __shfl_xor(sv, m); nm += __shfl_xor(nm, m);
        }
        if (lane == 0) { red[w] = sp; red[4 + w] = sv; red[8 + w] = nm; }
        __syncthreads();
        if (t == 0) {
            float SP = 0, SN = 0, NM = 0;
            for (int i = 0; i < 4; ++i) { SP += red[i]; SN += red[4 + i]; NM += red[8 + i]; }
            SP /= 256.f; SN /= 256.f; NM /= 256.f;
            out[0] = fmaxf(0.f, 0.2f + SN - SP) + 0.25f * (-NM);
        }
    }
}

extern "C" void kernel_launch(void* const* d_in, const int* in_sizes, int n_in,
                              void* d_out, int out_size, void* d_ws, size_t ws_size,
                              hipStream_t stream) {
    const float* fg = (const float*)d_in[0];
    const float* bg = (const float*)d_in[1];
    const float* F  = (const float*)d_in[2];
    const float* M  = (const float*)d_in[3];
    float* out = (float*)d_out;
    char* ws = (char*)d_ws;

    size_t o = 0;
    auto alloc = [&](size_t bytes) { size_t r = o; o += (bytes + 1023) & ~(size_t)1023; return r; };
    // zero region
    size_t off_hist1 = alloc(2 * 65536 * 4);
    size_t off_hist2 = alloc(2 * 65536 * 4);
    size_t off_ctrl  = alloc(64);
    size_t off_bar   = alloc(64);
    size_t off_cnts  = alloc(10 * 128 * 4);
    size_t off_sums  = alloc((size_t)10 * 65536 * 4);
    size_t zbytes = o;
    size_t off_sfg   = alloc(P_TOTAL * 4);
    size_t off_sbg   = alloc(P_TOTAL * 4);
    size_t off_inv   = alloc(P_TOTAL * 4);
    size_t off_pT    = alloc(512 * 128 * 4);
    size_t off_pwT   = alloc(2 * 64 * 512 * 4);
    size_t off_idx   = alloc(2 * 256 * 4);
    size_t off_ties  = alloc(2 * 512 * 4);
    size_t off_feats = alloc(512 * 512 * 4);
    size_t off_lp1   = alloc(256 * 8);
    size_t off_lp2   = alloc(256 * 8);
    size_t off_lp3   = alloc(256 * 4);

    unsigned* hist1 = (unsigned*)(ws + off_hist1);
    unsigned* hist2 = (unsigned*)(ws + off_hist2);
    int* ctrl   = (int*)(ws + off_ctrl);
    int* bar    = (int*)(ws + off_bar);
    float* cnts10 = (float*)(ws + off_cnts);
    float* sums10 = (float*)(ws + off_sums);
    float* sfg  = (float*)(ws + off_sfg);
    float* sbg  = (float*)(ws + off_sbg);
    float* inv  = (float*)(ws + off_inv);
    float* pT   = (float*)(ws + off_pT);
    float* pwT  = (float*)(ws + off_pwT);
    int* idx    = (int*)(ws + off_idx);
    int* ties   = (int*)(ws + off_ties);
    float* feats = (float*)(ws + off_feats);
    unsigned long long* lp1 = (unsigned long long*)(ws + off_lp1);
    unsigned long long* lp2 = (unsigned long long*)(ws + off_lp2);
    float* lp3 = (float*)(ws + off_lp3);

    hipMemsetAsync(ws, 0, zbytes, stream);
    k_init<<<256, 256, 0, stream>>>(fg, bg, pT, pwT);
    k_score<<<256, 512, 0, stream>>>(F, pT, M, sfg, sbg, inv, hist1);
    k_scan<<<2, 1024, 0, stream>>>(hist1, ctrl, 0);
    k_hist2<<<dim3(576, 2), 256, 0, stream>>>(sfg, sbg, ctrl, hist2);
    k_scan<<<2, 1024, 0, stream>>>(hist2, ctrl, 1);
    k_collect<<<dim3(576, 2), 256, 0, stream>>>(sfg, sbg, ctrl, idx, ties);
    k_finalize<<<1, 64, 0, stream>>>(ctrl, idx, ties);
    k_gather<<<512, 256, 0, stream>>>(F, inv, idx, feats);
    k_refine<<<256, 256, 0, stream>>>(feats, pwT, fg, bg, sums10, cnts10,
                                      lp1, lp2, lp3, out, bar);
}

// Round 7
// 990.773 us; speedup vs baseline: 1.7140x; 1.4488x over previous
//
#include <hip/hip_runtime.h>
#include <math.h>

#define P_TOTAL 147456
#define HW 9216
#define CHW (512*9216)

__device__ __forceinline__ unsigned f2key(float f) {
    unsigned u = __float_as_uint(f);
    return (u & 0x80000000u) ? ~u : (u | 0x80000000u);
}

// ---------- K0: protoT [c][128] (j=side*64+k), pwork [side][k][c], pwT [side][c][k] ----------
__global__ void k_init(const float* __restrict__ fg, const float* __restrict__ bg,
                       float* __restrict__ protoT, float* __restrict__ pwork,
                       float* __restrict__ pwT) {
    int i = blockIdx.x * 256 + threadIdx.x;   // 0..65535
    int side = i >> 15;
    int r = i & 32767;
    int k = r >> 9;
    int c = r & 511;
    float v = (side ? bg : fg)[k * 512 + c];
    protoT[c * 128 + side * 64 + k] = v;
    pwork[side * 32768 + k * 512 + c] = v;
    pwT[side * 32768 + c * 64 + k] = v;
}

// ---------- K1: scoring GEMM + combine + hist1, fused; (512,1) -> no VGPR spill ----------
__global__ __launch_bounds__(512, 1) void k_score(const float* __restrict__ F,
                                                  const float* __restrict__ protoT,
                                                  const float* __restrict__ M,
                                                  float* __restrict__ sfg,
                                                  float* __restrict__ sbg,
                                                  float* __restrict__ invout,
                                                  unsigned* __restrict__ hist) {
    __shared__ float lds[8192];               // 32 KB proto chunk [c][128 j]
    const int t = threadIdx.x;
    const int lane = t & 63;
    const int w = t >> 6;                     // 0..7 ; j range [16w, 16w+16)
    const int p0 = blockIdx.x * 576 + lane;   // 9216 % 576 == 0 -> one image per block
    const int n = p0 / HW;
    const int hw0 = p0 - n * HW;
    const float* Fb = F + (size_t)n * CHW;

    float acc[16][9];
#pragma unroll
    for (int jj = 0; jj < 16; ++jj)
#pragma unroll
        for (int i = 0; i < 9; ++i) acc[jj][i] = 0.f;
    float nn[9];
#pragma unroll
    for (int i = 0; i < 9; ++i) nn[i] = 0.f;

    auto ldch = [&](float (&dst)[9], int ch) {
        int chc = ch > 511 ? 511 : ch;
        const float* q = Fb + hw0 + (size_t)chc * HW;
#pragma unroll
        for (int i = 0; i < 9; ++i) dst[i] = q[i * 64];
    };
    auto kstep = [&](const float (&f)[9], int cc) {
        const float4* pv4 = (const float4*)(lds + cc * 128 + w * 16);
#pragma unroll
        for (int j4 = 0; j4 < 4; ++j4) {
            float4 bq = pv4[j4];
#pragma unroll
            for (int i = 0; i < 9; ++i) {
                acc[j4 * 4 + 0][i] = fmaf(f[i], bq.x, acc[j4 * 4 + 0][i]);
                acc[j4 * 4 + 1][i] = fmaf(f[i], bq.y, acc[j4 * 4 + 1][i]);
                acc[j4 * 4 + 2][i] = fmaf(f[i], bq.z, acc[j4 * 4 + 2][i]);
                acc[j4 * 4 + 3][i] = fmaf(f[i], bq.w, acc[j4 * 4 + 3][i]);
            }
        }
    };

    float fa[9], fb[9];
    ldch(fa, 0); ldch(fb, 1);
    int ch = 2;

    for (int chunk = 0; chunk < 8; ++chunk) {
        __syncthreads();
        {
            const float4* src = (const float4*)(protoT + chunk * 8192);
            float4* dst = (float4*)lds;
#pragma unroll
            for (int i2 = 0; i2 < 4; ++i2) dst[t + 512 * i2] = src[t + 512 * i2];
        }
        __syncthreads();
        for (int c2 = 0; c2 < 32; ++c2) {
            if (w == 0) {
#pragma unroll
                for (int i = 0; i < 9; ++i) nn[i] = fmaf(fa[i], fa[i], nn[i]);
            }
            kstep(fa, c2 * 2);
            ldch(fa, ch++);
            if (w == 0) {
#pragma unroll
                for (int i = 0; i < 9; ++i) nn[i] = fmaf(fb[i], fb[i], nn[i]);
            }
            kstep(fb, c2 * 2 + 1);
            ldch(fb, ch++);
        }
    }

    float m16[9];
#pragma unroll
    for (int i = 0; i < 9; ++i) {
        float mm = acc[0][i];
#pragma unroll
        for (int jj = 1; jj < 16; ++jj) mm = fmaxf(mm, acc[jj][i]);
        m16[i] = mm;
    }
    __syncthreads();
#pragma unroll
    for (int i = 0; i < 9; ++i) lds[w * 576 + i * 64 + lane] = m16[i];
    if (w == 0) {
#pragma unroll
        for (int i = 0; i < 9; ++i) lds[4608 + i * 64 + lane] = nn[i];
    }
    __syncthreads();
    for (int pi = t; pi < 576; pi += 512) {
        int p = blockIdx.x * 576 + pi;
        float fgm = fmaxf(fmaxf(lds[pi], lds[576 + pi]), fmaxf(lds[1152 + pi], lds[1728 + pi]));
        float bgm = fmaxf(fmaxf(lds[2304 + pi], lds[2880 + pi]), fmaxf(lds[3456 + pi], lds[4032 + pi]));
        float inv = 1.f / fmaxf(sqrtf(lds[4608 + pi]), 1e-8f);
        float mm = fminf(fmaxf(M[p], 0.f), 1.f);
        float sf = (1.f - fgm * inv) * mm;
        float sb = (1.f - bgm * inv) * (1.f - mm);
        sfg[p] = sf; sbg[p] = sb; invout[p] = inv;
        atomicAdd(&hist[f2key(sf) >> 16], 1u);
        atomicAdd(&hist[65536 + (f2key(sb) >> 16)], 1u);
    }
}

// ---------- scan / hist2 / collect / finalize (unchanged, proven) ----------
__global__ __launch_bounds__(1024) void k_scan(const unsigned* __restrict__ hist,
                                               int* __restrict__ ctrl, int pass) {
    __shared__ unsigned sd[1024];
    int side = blockIdx.x;
    const unsigned* h = hist + side * 65536;
    int t = threadIdx.x;
    unsigned partial = 0;
    for (int j = 0; j < 64; ++j) partial += h[65535 - (t * 64 + j)];
    sd[t] = partial;
    __syncthreads();
    for (int off = 1; off < 1024; off <<= 1) {
        unsigned v = (t >= off) ? sd[t - off] : 0u;
        __syncthreads();
        sd[t] += v;
        __syncthreads();
    }
    unsigned incl = sd[t];
    unsigned excl = incl - partial;
    unsigned target = (pass == 0) ? 256u : (unsigned)ctrl[side * 8 + 1];
    if (excl < target && target <= incl) {
        unsigned cum = excl;
        for (int j = 0; j < 64; ++j) {
            int b = 65535 - (t * 64 + j);
            unsigned c = h[b];
            if (cum + c >= target) {
                if (pass == 0) {
                    ctrl[side * 8 + 0] = b;
                    ctrl[side * 8 + 1] = (int)(target - cum);
                } else {
                    unsigned vkey = ((unsigned)ctrl[side * 8 + 0] << 16) | (unsigned)b;
                    ctrl[side * 8 + 2] = (int)vkey;
                    int n_gt = (int)(256u - (unsigned)ctrl[side * 8 + 1] + cum);
                    ctrl[side * 8 + 3] = n_gt;
                    ctrl[side * 8 + 4] = 256 - n_gt;
                }
                break;
            }
            cum += c;
        }
    }
}

__global__ void k_hist2(const float* __restrict__ sfg, const float* __restrict__ sbg,
                        const int* __restrict__ ctrl, unsigned* __restrict__ hist2) {
    int side = blockIdx.y;
    int p = blockIdx.x * 256 + threadIdx.x;
    float s = side ? sbg[p] : sfg[p];
    unsigned key = f2key(s);
    if ((int)(key >> 16) == ctrl[side * 8 + 0])
        atomicAdd(&hist2[side * 65536 + (key & 0xffffu)], 1u);
}

__global__ void k_collect(const float* __restrict__ sfg, const float* __restrict__ sbg,
                          int* __restrict__ ctrl, int* __restrict__ idx, int* __restrict__ ties) {
    int side = blockIdx.y;
    int p = blockIdx.x * 256 + threadIdx.x;
    float s = side ? sbg[p] : sfg[p];
    unsigned key = f2key(s);
    unsigned vkey = (unsigned)ctrl[side * 8 + 2];
    if (key > vkey) {
        int pos = atomicAdd(&ctrl[side * 8 + 5], 1);
        idx[side * 256 + pos] = p;
    } else if (key == vkey) {
        int pos = atomicAdd(&ctrl[side * 8 + 6], 1);
        if (pos < 512) ties[side * 512 + pos] = p;
    }
}

__global__ void k_finalize(int* __restrict__ ctrl, int* __restrict__ idx, int* __restrict__ ties) {
    int side = threadIdx.x;
    if (side >= 2) return;
    int n_gt = ctrl[side * 8 + 3];
    int need = ctrl[side * 8 + 4];
    int cnt = ctrl[side * 8 + 6];
    if (cnt > 512) cnt = 512;
    int* tb = ties + side * 512;
    for (int q = 0; q < need; ++q) {
        int mi = q;
        for (int j = q + 1; j < cnt; ++j) if (tb[j] < tb[mi]) mi = j;
        int tmp = tb[q]; tb[q] = tb[mi]; tb[mi] = tmp;
        idx[side * 256 + n_gt + q] = tb[q];
    }
}

__global__ void k_gather(const float* __restrict__ F, const float* __restrict__ inv,
                         const int* __restrict__ idx, float* __restrict__ feats) {
    int b = blockIdx.x;              // 0..511
    int side = b >> 8, j = b & 255;
    int p = idx[side * 256 + j];
    float iv = inv[p];
    int n = p / HW, hw = p - n * HW;
    const float* Fp = F + (size_t)n * CHW + hw;
    float* o = feats + (size_t)(side * 256 + j) * 512;
    for (int c = threadIdx.x; c < 512; c += 256)
        o[c] = Fp[(size_t)c * HW] * iv;
}

// ---------- refinement: assign (wave per point, lane = cluster; coalesced pwT) ----------
__global__ __launch_bounds__(256) void k_assign(const float* __restrict__ feats,
                                                const float* __restrict__ pwT,
                                                float* __restrict__ sums,
                                                float* __restrict__ counts) {
    int w = blockIdx.x * 4 + (threadIdx.x >> 6);   // 0..511
    int lane = threadIdx.x & 63;
    int side = w >> 8, j = w & 255;
    const float* fr = feats + (size_t)(side * 256 + j) * 512;   // wave-uniform -> s_load
    const float* pT = pwT + (size_t)side * 32768;
    float dot = 0.f;
#pragma unroll 8
    for (int c = 0; c < 512; ++c)
        dot = fmaf(fr[c], pT[c * 64 + lane], dot);              // coalesced 64-wide
    float bv = dot; int bi = lane;
#pragma unroll
    for (int m = 32; m >= 1; m >>= 1) {
        float ov = __shfl_xor(bv, m);
        int oi = __shfl_xor(bi, m);
        if (ov > bv || (ov == bv && oi < bi)) { bv = ov; bi = oi; }
    }
    if (lane == 0) atomicAdd(&counts[side * 64 + bi], 1.f);
    float* srow = sums + (size_t)side * 32768 + (size_t)bi * 512;
#pragma unroll
    for (int i = 0; i < 8; ++i) {
        int c = lane + i * 64;
        atomicAdd(&srow[c], fr[c]);
    }
}

// ---------- refinement: update protos (wave per cluster); maintains both layouts ----------
__global__ __launch_bounds__(64) void k_update(float* __restrict__ pwork,
                                               float* __restrict__ pwT,
                                               float* __restrict__ sums,
                                               float* __restrict__ counts,
                                               float step) {
    int side = blockIdx.x >> 6, k = blockIdx.x & 63;
    int lane = threadIdx.x;
    float cnt = counts[side * 64 + k];
    float* srow = sums + (size_t)side * 32768 + (size_t)k * 512;
    float* prow = pwork + (size_t)side * 32768 + (size_t)k * 512;
    float* pT = pwT + (size_t)side * 32768;
    float bl[8]; float n2 = 0.f;
#pragma unroll
    for (int i = 0; i < 8; ++i) {
        int c = lane + i * 64;
        float mean = srow[c] / fmaxf(cnt, 1.f);
        float v = (1.f - step) * prow[c] + step * mean;
        bl[i] = v; n2 = fmaf(v, v, n2);
        srow[c] = 0.f;
    }
#pragma unroll
    for (int m = 32; m >= 1; m >>= 1) n2 += __shfl_xor(n2, m);
    float inv = 1.f / fmaxf(sqrtf(n2), 1e-8f);
    if (cnt > 0.f) {
#pragma unroll
        for (int i = 0; i < 8; ++i) {
            int c = lane + i * 64;
            float v = bl[i] * inv;
            prow[c] = v;
            pT[(size_t)c * 64 + k] = v;
        }
    }
    if (lane == 0) counts[side * 64 + k] = 0.f;
}

// ---------- loss partials: wave per row (r0-proven) ----------
__global__ __launch_bounds__(256) void k_losspart(const float* __restrict__ feats,
                                                  const float* __restrict__ pwork,
                                                  float* __restrict__ lpart) {
    int w = blockIdx.x * 4 + (threadIdx.x >> 6);  // 0..511
    int lane = threadIdx.x & 63;
    int half = w >> 8, j = w & 255;
    const float4* fr = (const float4*)(feats + (size_t)(half * 256 + j) * 512);
    const float4* pf = (const float4*)(pwork + (size_t)lane * 512);
    const float4* pb = (const float4*)(pwork + 32768 + (size_t)lane * 512);
    if (half == 0) {
        float d1 = 0.f, d2 = 0.f;
        for (int c = 0; c < 128; ++c) {
            float4 a = fr[c], x = pf[c], y = pb[c];
            d1 = fmaf(a.x, x.x, d1); d1 = fmaf(a.y, x.y, d1);
            d1 = fmaf(a.z, x.z, d1); d1 = fmaf(a.w, x.w, d1);
            d2 = fmaf(a.x, y.x, d2); d2 = fmaf(a.y, y.y, d2);
            d2 = fmaf(a.z, y.z, d2); d2 = fmaf(a.w, y.w, d2);
        }
        float smax = d1;
        for (int m = 32; m >= 1; m >>= 1) smax = fmaxf(smax, __shfl_xor(smax, m));
        float a = d1 / 0.07f, b = d2 / 0.07f;
        float m1 = a;
        for (int m = 32; m >= 1; m >>= 1) m1 = fmaxf(m1, __shfl_xor(m1, m));
        float mb = b;
        for (int m = 32; m >= 1; m >>= 1) mb = fmaxf(mb, __shfl_xor(mb, m));
        float md = fmaxf(m1, mb);
        float sn = expf(a - m1);
        for (int m = 32; m >= 1; m >>= 1) sn += __shfl_xor(sn, m);
        float sdn = expf(a - md) + expf(b - md);
        for (int m = 32; m >= 1; m >>= 1) sdn += __shfl_xor(sdn, m);
        float num = m1 + logf(sn);
        float den = md + logf(sdn);
        if (lane == 0) { lpart[j] = smax; lpart[512 + j] = num - den; }
    } else {
        float d1 = 0.f;
        for (int c = 0; c < 128; ++c) {
            float4 a = fr[c], x = pf[c];
            d1 = fmaf(a.x, x.x, d1); d1 = fmaf(a.y, x.y, d1);
            d1 = fmaf(a.z, x.z, d1); d1 = fmaf(a.w, x.w, d1);
        }
        float smax = d1;
        for (int m = 32; m >= 1; m >>= 1) smax = fmaxf(smax, __shfl_xor(smax, m));
        if (lane == 0) lpart[256 + j] = smax;
    }
}

// ---------- final scalar loss ----------
__global__ __launch_bounds__(256) void k_final(const float* __restrict__ lpart,
                                               float* __restrict__ out) {
    __shared__ float red[3][4];
    int t = threadIdx.x;
    float sp = lpart[t], sn = lpart[256 + t], nm = lpart[512 + t];
    for (int m = 32; m >= 1; m >>= 1) {
        sp += __shfl_xor(sp, m); sn += __shfl_xor(sn, m); nm += __shfl_xor(nm, m);
    }
    int wv = t >> 6;
    if ((t & 63) == 0) { red[0][wv] = sp; red[1][wv] = sn; red[2][wv] = nm; }
    __syncthreads();
    if (t == 0) {
        float SP = 0, SN = 0, NM = 0;
        for (int i = 0; i < 4; ++i) { SP += red[0][i]; SN += red[1][i]; NM += red[2][i]; }
        SP /= 256.f; SN /= 256.f; NM /= 256.f;
        out[0] = fmaxf(0.f, 0.2f + SN - SP) + 0.25f * (-NM);
    }
}

// ---------- blended refined protos ----------
__global__ __launch_bounds__(64) void k_refined(const float* __restrict__ fg,
                                                const float* __restrict__ bg,
                                                const float* __restrict__ pwork,
                                                float* __restrict__ out) {
    int side = blockIdx.x >> 6, k = blockIdx.x & 63;
    int lane = threadIdx.x;
    const float* proto = (side ? bg : fg) + (size_t)k * 512;
    const float* prow = pwork + (size_t)side * 32768 + (size_t)k * 512;
    float bl[8]; float n2 = 0.f;
#pragma unroll
    for (int i = 0; i < 8; ++i) {
        int c = lane + i * 64;
        float v = 0.7f * proto[c] + 0.3f * prow[c];
        bl[i] = v; n2 = fmaf(v, v, n2);
    }
#pragma unroll
    for (int m = 32; m >= 1; m >>= 1) n2 += __shfl_xor(n2, m);
    float inv = 1.f / fmaxf(sqrtf(n2), 1e-8f);
    float* o = out + 1 + (size_t)side * 32768 + (size_t)k * 512;
#pragma unroll
    for (int i = 0; i < 8; ++i) o[lane + i * 64] = bl[i] * inv;
}

extern "C" void kernel_launch(void* const* d_in, const int* in_sizes, int n_in,
                              void* d_out, int out_size, void* d_ws, size_t ws_size,
                              hipStream_t stream) {
    const float* fg = (const float*)d_in[0];
    const float* bg = (const float*)d_in[1];
    const float* F  = (const float*)d_in[2];
    const float* M  = (const float*)d_in[3];
    float* out = (float*)d_out;
    char* ws = (char*)d_ws;

    size_t o = 0;
    auto alloc = [&](size_t bytes) { size_t r = o; o += (bytes + 1023) & ~(size_t)1023; return r; };
    // zero region
    size_t off_hist1 = alloc(2 * 65536 * 4);
    size_t off_hist2 = alloc(2 * 65536 * 4);
    size_t off_ctrl  = alloc(64);
    size_t off_cnts  = alloc(2 * 64 * 4);
    size_t off_sums  = alloc(2 * 64 * 512 * 4);
    size_t zbytes = o;
    size_t off_sfg   = alloc(P_TOTAL * 4);
    size_t off_sbg   = alloc(P_TOTAL * 4);
    size_t off_inv   = alloc(P_TOTAL * 4);
    size_t off_pT    = alloc(512 * 128 * 4);
    size_t off_pwork = alloc(2 * 64 * 512 * 4);
    size_t off_pwT   = alloc(2 * 512 * 64 * 4);
    size_t off_idx   = alloc(2 * 256 * 4);
    size_t off_ties  = alloc(2 * 512 * 4);
    size_t off_feats = alloc(512 * 512 * 4);
    size_t off_lpart = alloc(768 * 4);

    unsigned* hist1 = (unsigned*)(ws + off_hist1);
    unsigned* hist2 = (unsigned*)(ws + off_hist2);
    int* ctrl   = (int*)(ws + off_ctrl);
    float* cnts = (float*)(ws + off_cnts);
    float* sums = (float*)(ws + off_sums);
    float* sfg  = (float*)(ws + off_sfg);
    float* sbg  = (float*)(ws + off_sbg);
    float* inv  = (float*)(ws + off_inv);
    float* pT   = (float*)(ws + off_pT);
    float* pwork = (float*)(ws + off_pwork);
    float* pwT  = (float*)(ws + off_pwT);
    int* idx    = (int*)(ws + off_idx);
    int* ties   = (int*)(ws + off_ties);
    float* feats = (float*)(ws + off_feats);
    float* lpart = (float*)(ws + off_lpart);

    hipMemsetAsync(ws, 0, zbytes, stream);
    k_init<<<256, 256, 0, stream>>>(fg, bg, pT, pwork, pwT);
    k_score<<<256, 512, 0, stream>>>(F, pT, M, sfg, sbg, inv, hist1);
    k_scan<<<2, 1024, 0, stream>>>(hist1, ctrl, 0);
    k_hist2<<<dim3(576, 2), 256, 0, stream>>>(sfg, sbg, ctrl, hist2);
    k_scan<<<2, 1024, 0, stream>>>(hist2, ctrl, 1);
    k_collect<<<dim3(576, 2), 256, 0, stream>>>(sfg, sbg, ctrl, idx, ties);
    k_finalize<<<1, 64, 0, stream>>>(ctrl, idx, ties);
    k_gather<<<512, 256, 0, stream>>>(F, inv, idx, feats);
    for (int it = 0; it < 10; ++it) {
        k_assign<<<128, 256, 0, stream>>>(feats, pwT, sums, cnts);
        k_update<<<128, 64, 0, stream>>>(pwork, pwT, sums, cnts, (float)(0.1 / (1.0 + 0.5 * it)));
    }
    k_losspart<<<128, 256, 0, stream>>>(feats, pwork, lpart);
    k_final<<<1, 256, 0, stream>>>(lpart, out);
    k_refined<<<128, 64, 0, stream>>>(fg, bg, pwork, out);
}